// Round 13
// baseline (330.695 us; speedup 1.0000x reference)
//
#include <hip/hip_runtime.h>

typedef float v4f __attribute__((ext_vector_type(4)));

namespace {
constexpr int B_     = 8;
constexpr int NT_    = 256;
constexpr int NX_    = 256;
constexpr int NREC_  = 64;
constexpr int PIECES = 16;             // 128 blocks
constexpr int IROWS  = 16;             // interior rows per strip
constexpr int G      = 32;             // R20: double round length -> 7 exchanges
constexpr int ROUNDS = NT_ / G;        // 8
constexpr int NBANDS = 10;             // 10 waves x 8 rows = 80 ext rows
constexpr int NTHR   = NBANDS * 64;    // 640 threads
constexpr int NBLK   = B_ * PIECES;    // 128 blocks
constexpr float DT2  = 1e-6f;          // DT*DT
constexpr float KLAP = 1e-8f;          // DT*DT/(DH*DH)
constexpr size_t FLAGS_BYTES = 4096;
constexpr int RCAP = 6;
} // namespace

__device__ __forceinline__ float dpp_shr1(float v) {
    return __int_as_float(__builtin_amdgcn_update_dpp(
        0, __float_as_int(v), 0x138 /*WAVE_SHR1*/, 0xF, 0xF, true));
}
__device__ __forceinline__ float dpp_shl1(float v) {
    return __int_as_float(__builtin_amdgcn_update_dpp(
        0, __float_as_int(v), 0x130 /*WAVE_SHL1*/, 0xF, 0xF, true));
}

// R19 post-mortem: E ~= 6.4us/exchange is PHYSICAL MALL round-trip latency --
// invariant under fences (R10), handshake shape (R11), barrier removal (R19),
// full async (R18). Only lever left: do it FEWER times.
// R20: G=32 -> 7 exchanges (E-term 96us -> ~49us). 8-row bands (forced by the
// 1024-thread cap) are safe here at 10 waves = 2.5/SIMD (R16's failure was
// 1.25/SIMD occupancy, not the band width). Components individually proven:
// R16's 8-row step + R15's two-hop exchange, both bit-identical-verified.
// Trapezoid cuts (row-life frontier proof): {7,15,23,31,32,32,31,23,15,7}.
// Two-hop: bands 0,1<-blk-2; 2,3<-blk-1; 6,7<-blk+1; 8,9<-blk+2.
__device__ __forceinline__ void store_v4_sys(float* p, v4f v) {
    asm volatile("global_store_dwordx4 %0, %1, off sc0 sc1"
                 :: "v"(p), "v"(v) : "memory");
}
__device__ __forceinline__ v4f load_v4_sys(const float* p) {
    v4f r;
    asm volatile("global_load_dwordx4 %0, %1, off sc0 sc1"
                 : "=v"(r) : "v"(p) : "memory");
    return r;
}

extern "C" __global__
__attribute__((amdgpu_flat_work_group_size(NTHR, NTHR), amdgpu_waves_per_eu(2, 4)))
void wave_reg_kernel(const float* __restrict__ x,
                     const float* __restrict__ vp,
                     const int* __restrict__ src_loc,
                     const int* __restrict__ rec_loc,
                     float* __restrict__ out,
                     int* __restrict__ flags,   // [128] monotone round counters
                     float* __restrict__ gbuf)  // [par2][128][lvl2][16][256]
{
    __shared__ float pub[2][2][NBANDS][256];  // 40 KB [par][top/bot][band][col]
    __shared__ float wav[NT_];                // 1 KB wavelet
    __shared__ float recbuf[G][NREC_];        // 8 KB receiver staging
    __shared__ unsigned char recown[NREC_];

    const int bid  = blockIdx.x;
    const int b    = bid & 7;
    const int p    = bid >> 3;             // 0..15
    const int blk  = b * PIECES + p;
    const int tid  = threadIdx.x;
    const int band = tid >> 6;             // wave id 0..9 -> 8 ext rows
    const int lane = tid & 63;
    const int c0   = lane << 2;            // first owned col (0..252)
    const int grt  = p * IROWS - G + (band << 3);  // global row of owned row 0

    // trapezoid: compute in-round step k (1-based) iff k<=cut; publish iff
    // k<=cut+1. cuts {7,15,23,31,32,32,31,23,15,7}.
    const int cut = (band < 4) ? ((band << 3) + 7)
                  : ((band < 6) ? G : (79 - (band << 3)));

    if (tid < NT_) wav[tid] = x[b * NT_ + tid];
    if (tid < NREC_) {
        int rz = rec_loc[(b * NREC_ + tid) * 2 + 0];
        recown[tid] = (rz >= p * IROWS && rz < p * IROWS + IROWS) ? 1 : 0;
    }

    // cf = vp^2*DT^2/DH^2 masked; cf2 = 2 - 4*cf
    v4f cf[8], cf2[8];
#pragma unroll
    for (int i = 0; i < 8; ++i) {
        int gr = grt + i;
        int crow = gr < 0 ? 0 : (gr > 255 ? 255 : gr);
        bool rowok = (gr >= 1) && (gr <= 254);
        v4f vv = *(const v4f*)&vp[crow * NX_ + c0];
        float cc[4];
#pragma unroll
        for (int k = 0; k < 4; ++k) {
            int col = c0 + k;
            float vk = (k == 0) ? vv.x : (k == 1) ? vv.y : (k == 2) ? vv.z : vv.w;
            cc[k] = (rowok && col >= 1 && col <= 254) ? vk * vk * KLAP : 0.f;
        }
        cf[i].x = cc[0]; cf[i].y = cc[1]; cf[i].z = cc[2]; cf[i].w = cc[3];
        cf2[i].x = 2.f - 4.f * cc[0]; cf2[i].y = 2.f - 4.f * cc[1];
        cf2[i].z = 2.f - 4.f * cc[2]; cf2[i].w = 2.f - 4.f * cc[3];
    }

    // source ownership (ghost rows included: ghost evolution must replay it)
    const int sz = src_loc[b * 2 + 0], sx = src_loc[b * 2 + 1];
    const int si = sz - grt;               // 0..7 if owned row
    const int sj = sx - c0;                // 0..3 if owned col
    const bool has_src = ((unsigned)si < 8u) && ((unsigned)sj < 4u);
    const bool wave_has_src = __any(has_src);

    // receiver slots: interior owner only (bands 4,5). pk=(r<<5)|(i<<2)|j
    int rs[RCAP]; int rcnt = 0;
#pragma unroll 1
    for (int r = 0; r < NREC_; ++r) {
        int rz = rec_loc[(b * NREC_ + r) * 2 + 0];
        int rx = rec_loc[(b * NREC_ + r) * 2 + 1];
        int i = rz - grt, j = rx - c0;
        if (rz >= p * IROWS && rz < p * IROWS + IROWS &&
            (unsigned)i < 8u && (unsigned)j < 4u) {
            if (rcnt < RCAP) rs[rcnt] = (r << 5) | (i << 2) | j;
            ++rcnt;
        }
    }
    if (rcnt > RCAP) rcnt = RCAP;
    const bool wave_has_rec = __any(rcnt > 0);
    float* outb = out + (size_t)b * NT_ * NREC_;

    v4f A[8], Bv[8];
    {
        v4f z = {0.f, 0.f, 0.f, 0.f};
#pragma unroll
        for (int i = 0; i < 8; ++i) { A[i] = z; Bv[i] = z; }
    }

    // gbuf slab: [par][blk][lvl][row(0..15)][col]; interior = the slab.
    auto gptr = [&](int e, int bk, int lvl, int rr) -> float* {
        return gbuf + ((((size_t)(e & 1) * NBLK + bk) * 2 + lvl) * 16 + rr) * 256;
    };

// one stencil row: literal index I only (rule #20)
#define ROW(I, NV, SV) do {                                                   \
    float wv = dpp_shr1(C[I].w);   /* col c0-1 (lane0 -> 0: cf=0 masks) */    \
    float ev = dpp_shl1(C[I].x);   /* col c0+4 (lane63 -> 0: cf=0 masks) */   \
    v4f hn;                                                                   \
    { float sm = ((NV).x + (SV).x) + (wv     + C[I].y);                       \
      hn.x = fmaf(cf[I].x, sm, fmaf(cf2[I].x, C[I].x, -P[I].x)); }            \
    { float sm = ((NV).y + (SV).y) + (C[I].x + C[I].z);                       \
      hn.y = fmaf(cf[I].y, sm, fmaf(cf2[I].y, C[I].y, -P[I].y)); }            \
    { float sm = ((NV).z + (SV).z) + (C[I].y + C[I].w);                       \
      hn.z = fmaf(cf[I].z, sm, fmaf(cf2[I].z, C[I].z, -P[I].z)); }            \
    { float sm = ((NV).w + (SV).w) + (C[I].z + ev);                           \
      hn.w = fmaf(cf[I].w, sm, fmaf(cf2[I].w, C[I].w, -P[I].w)); }            \
    P[I] = hn;                                                                \
} while (0)

    // one step: P <- update(C, P); P becomes current. par = t&1.
    auto step = [&](v4f (&C)[8], v4f (&P)[8], int t, int par) {
        const int k = (t & (G - 1)) + 1;
        if (k <= cut + 1) {                 // publish window = compute window +1
            *(v4f*)&pub[par][0][band][c0] = C[0];  // top row (S halo of band-1)
            *(v4f*)&pub[par][1][band][c0] = C[7];  // bottom row (N halo of band+1)
        }
        __syncthreads();
        if (k > cut) return;                // band dead for rest of round
        v4f nn, ss;
        if (band > 0)          nn = *(const v4f*)&pub[par][1][band - 1][c0];
        else                   { nn.x = 0.f; nn.y = 0.f; nn.z = 0.f; nn.w = 0.f; }
        if (band < NBANDS - 1) ss = *(const v4f*)&pub[par][0][band + 1][c0];
        else                   { ss.x = 0.f; ss.y = 0.f; ss.z = 0.f; ss.w = 0.f; }
        // inner rows first: their VALU hides the halo ds_read latency
        ROW(1, C[0], C[2]);
        ROW(2, C[1], C[3]);
        ROW(3, C[2], C[4]);
        ROW(4, C[3], C[5]);
        ROW(5, C[4], C[6]);
        ROW(6, C[5], C[7]);
        ROW(0, nn,   C[1]);
        ROW(7, C[6], ss);
        if (wave_has_src) {
            const float sv = DT2 * wav[t];
#pragma unroll
            for (int i = 0; i < 8; ++i) {
                if (has_src && si == i) {
                    if      (sj == 0) P[i].x += sv;
                    else if (sj == 1) P[i].y += sv;
                    else if (sj == 2) P[i].z += sv;
                    else              P[i].w += sv;
                }
            }
        }
        if (wave_has_rec) {
#pragma unroll
            for (int kk = 0; kk < RCAP; ++kk) {
                if (rcnt > kk) {
                    int pk = rs[kk];
                    int i = (pk >> 2) & 7, j = pk & 3, r = pk >> 5;
                    v4f lo = (i & 2) ? ((i & 1) ? P[3] : P[2])
                                     : ((i & 1) ? P[1] : P[0]);
                    v4f hi = (i & 2) ? ((i & 1) ? P[7] : P[6])
                                     : ((i & 1) ? P[5] : P[4]);
                    v4f rw = (i & 4) ? hi : lo;
                    float c01 = (j & 1) ? rw.y : rw.x;
                    float c23 = (j & 1) ? rw.w : rw.z;
                    recbuf[t & (G - 1)][r] = (j & 2) ? c23 : c01;
                }
            }
        }
        // no trailing barrier: next step uses pub[par^1] (parity double-buffer)
    };

    // early publish of prev level (Bv final before the round's last step):
    // store drain overlaps the final step. Interior bands 4,5.
    auto publish_prev = [&](int e) {
        if (band == 4 || band == 5) {
            int rr0 = (band - 4) << 3;     // slab rows 0..7 / 8..15
#pragma unroll
            for (int i = 0; i < 8; ++i)
                store_v4_sys(&gptr(e, blk, 1, rr0 + i)[c0], Bv[i]);
        }
    };

    // two-hop fence-free exchange (R15-proven pattern, 8-row bands).
    auto exchange = [&](int e) {
        if (band == 4 || band == 5) {      // publish interior, cur level
            int rr0 = (band - 4) << 3;
#pragma unroll
            for (int i = 0; i < 8; ++i)
                store_v4_sys(&gptr(e, blk, 0, rr0 + i)[c0], A[i]);
        }
        __syncthreads();                   // drains each wave's vmcnt first
        if (tid == 0)                      // fire-and-forget; neighbors poll
            __hip_atomic_store(&flags[blk], e + 1, __ATOMIC_RELAXED,
                               __HIP_MEMORY_SCOPE_SYSTEM);
        if (band < 2 && p >= 2) {          // ext rows 0..15 <- blk-2 interior
            if (lane == 0)
                while (__hip_atomic_load(&flags[blk - 2], __ATOMIC_RELAXED,
                                         __HIP_MEMORY_SCOPE_SYSTEM) < e + 1)
                    __builtin_amdgcn_s_sleep(1);
            int rr0 = (band & 1) << 3;
#pragma unroll
            for (int i = 0; i < 8; ++i) {
                A[i]  = load_v4_sys(&gptr(e, blk - 2, 0, rr0 + i)[c0]);
                Bv[i] = load_v4_sys(&gptr(e, blk - 2, 1, rr0 + i)[c0]);
            }
        }
        if (band >= 2 && band < 4 && p >= 1) {  // ext 16..31 <- blk-1
            if (lane == 0)
                while (__hip_atomic_load(&flags[blk - 1], __ATOMIC_RELAXED,
                                         __HIP_MEMORY_SCOPE_SYSTEM) < e + 1)
                    __builtin_amdgcn_s_sleep(1);
            int rr0 = (band & 1) << 3;
#pragma unroll
            for (int i = 0; i < 8; ++i) {
                A[i]  = load_v4_sys(&gptr(e, blk - 1, 0, rr0 + i)[c0]);
                Bv[i] = load_v4_sys(&gptr(e, blk - 1, 1, rr0 + i)[c0]);
            }
        }
        if (band >= 6 && band < 8 && p < PIECES - 1) {  // ext 48..63 <- blk+1
            if (lane == 0)
                while (__hip_atomic_load(&flags[blk + 1], __ATOMIC_RELAXED,
                                         __HIP_MEMORY_SCOPE_SYSTEM) < e + 1)
                    __builtin_amdgcn_s_sleep(1);
            int rr0 = (band & 1) << 3;
#pragma unroll
            for (int i = 0; i < 8; ++i) {
                A[i]  = load_v4_sys(&gptr(e, blk + 1, 0, rr0 + i)[c0]);
                Bv[i] = load_v4_sys(&gptr(e, blk + 1, 1, rr0 + i)[c0]);
            }
        }
        if (band >= 8 && p < PIECES - 2) {  // ext 64..79 <- blk+2
            if (lane == 0)
                while (__hip_atomic_load(&flags[blk + 2], __ATOMIC_RELAXED,
                                         __HIP_MEMORY_SCOPE_SYSTEM) < e + 1)
                    __builtin_amdgcn_s_sleep(1);
            int rr0 = (band & 1) << 3;
#pragma unroll
            for (int i = 0; i < 8; ++i) {
                A[i]  = load_v4_sys(&gptr(e, blk + 2, 0, rr0 + i)[c0]);
                Bv[i] = load_v4_sys(&gptr(e, blk + 2, 1, rr0 + i)[c0]);
            }
        }
        asm volatile("s_waitcnt vmcnt(0)" ::: "memory");  // rule #18
        __builtin_amdgcn_sched_barrier(0);
        __syncthreads();                   // all waves aligned for next round
    };

    int t = 0;
#pragma unroll 1
    for (int e = 0; e < ROUNDS; ++e) {
#pragma unroll 1
        for (int s = 0; s < G; s += 2) {
            step(A, Bv, t, 0);      // t even: cur=A, par=0
            if (s == G - 2 && e < ROUNDS - 1)
                publish_prev(e);    // Bv = lvl t_end-1 final; overlap drain
            step(Bv, A, t + 1, 1);  // t odd:  cur=B, par=1
            t += 2;
        }
        // flush this round's receiver samples (G*NREC=2048 slots, 640 thr)
        __syncthreads();           // recbuf writes came from scattered owners
#pragma unroll 1
        for (int idx = tid; idx < G * NREC_; idx += NTHR) {
            int s = idx >> 6, r = idx & 63;
            if (recown[r]) outb[(e * G + s) * NREC_ + r] = recbuf[s][r];
        }
        if (e < ROUNDS - 1) exchange(e);
    }
#undef ROW
}

extern "C" void kernel_launch(void* const* d_in, const int* in_sizes, int n_in,
                              void* d_out, int out_size, void* d_ws, size_t ws_size,
                              hipStream_t stream) {
    const float* x   = (const float*)d_in[0];
    const float* vp  = (const float*)d_in[1];
    const int*   src = (const int*)d_in[2];
    const int*   rec = (const int*)d_in[3];
    float*       o   = (float*)d_out;
    int*   flags = (int*)d_ws;
    float* gbuf  = (float*)((char*)d_ws + FLAGS_BYTES);
    (void)hipMemsetAsync(d_ws, 0, FLAGS_BYTES, stream);   // flags must start at 0
    hipLaunchKernelGGL(wave_reg_kernel, dim3(NBLK), dim3(NTHR), 0, stream,
                       x, vp, src, rec, o, flags, gbuf);
}

// Round 14
// 288.218 us; speedup vs baseline: 1.1474x; 1.1474x over previous
//
#include <hip/hip_runtime.h>

typedef float v4f __attribute__((ext_vector_type(4)));

namespace {
constexpr int B_     = 8;
constexpr int NT_    = 256;
constexpr int NX_    = 256;
constexpr int NREC_  = 64;
constexpr int PIECES = 32;             // 256 blocks -> all 256 CUs
constexpr int IROWS  = 8;              // interior rows per strip
constexpr int GN     = 24;             // normal round length (ghost width)
constexpr int GL     = 16;             // last round length (10*24+16 = 256)
constexpr int NRND   = 11;             // 10 full rounds + 1 short (10 exchanges)
constexpr int NB     = 14;             // 14 bands x 4 rows = 56 ext rows
constexpr int NTHR   = NB * 64;        // 896 threads (3.5 waves/SIMD)
constexpr int NBLK   = B_ * PIECES;    // 256 blocks
constexpr float DT2  = 1e-6f;          // DT*DT
constexpr float KLAP = 1e-8f;          // DT*DT/(DH*DH)
constexpr size_t FLAGS_BYTES = 4096;
constexpr int RCAP = 6;
} // namespace

__device__ __forceinline__ float dpp_shr1(float v) {
    return __int_as_float(__builtin_amdgcn_update_dpp(
        0, __float_as_int(v), 0x138 /*WAVE_SHR1*/, 0xF, 0xF, true));
}
__device__ __forceinline__ float dpp_shl1(float v) {
    return __int_as_float(__builtin_amdgcn_update_dpp(
        0, __float_as_int(v), 0x130 /*WAVE_SHL1*/, 0xF, 0xF, true));
}

// Model (R8..R20 fits): wall = 256 x chain + Nexch x E.  chain ~= 560ns ONLY
// with 4-row bands at >=3 waves/SIMD (R20: 8-row bands -> 907ns, regression);
// E ~= 6.4us is physical MALL round-trip, invariant to protocol shape
// (R10/R11/R14/R18/R19). R21: cut Nexch 15 -> 10 while KEEPING the 4-row-band
// R13 step verbatim: G=24 (IROWS=8, 56 ext rows = 14 bands, 896 thr), 10 full
// rounds + one G=16 round. Ghost (24 rows) spans THREE neighbor interiors ->
// three-hop refill (R15's proven two-hop pattern, one hop deeper). Trapezoid
// cuts {3,7,11,15,19,23 | 24,24 | mirror}, capped at G in the last round;
// same frontier proof (publish window = cut+1) -> bit-identical.
__device__ __forceinline__ void store_v4_sys(float* p, v4f v) {
    asm volatile("global_store_dwordx4 %0, %1, off sc0 sc1"
                 :: "v"(p), "v"(v) : "memory");
}
__device__ __forceinline__ v4f load_v4_sys(const float* p) {
    v4f r;
    asm volatile("global_load_dwordx4 %0, %1, off sc0 sc1"
                 : "=v"(r) : "v"(p) : "memory");
    return r;
}

extern "C" __global__
__attribute__((amdgpu_flat_work_group_size(NTHR, NTHR), amdgpu_waves_per_eu(4, 4)))
void wave_reg_kernel(const float* __restrict__ x,
                     const float* __restrict__ vp,
                     const int* __restrict__ src_loc,
                     const int* __restrict__ rec_loc,
                     float* __restrict__ out,
                     int* __restrict__ flags,   // [256] monotone round counters
                     float* __restrict__ gbuf)  // [par2][256][lvl2][8][256]
{
    __shared__ float pub[2][2][NB][256];   // 56 KB: [par][top/bot][band][col]
    __shared__ float wav[NT_];             // 1 KB wavelet
    __shared__ float recbuf[GN][NREC_];    // 6 KB receiver staging (per round)
    __shared__ unsigned char recown[NREC_];// per-rec ownership of this block

    const int bid  = blockIdx.x;
    const int b    = bid & 7;
    const int p    = bid >> 3;             // 0..31
    const int blk  = b * PIECES + p;
    const int tid  = threadIdx.x;
    const int band = tid >> 6;             // wave id 0..13 -> 4 ext rows
    const int lane = tid & 63;
    const int c0   = lane << 2;            // first owned col (0..252)
    const int grt  = p * IROWS - GN + (band << 2); // global row of owned row 0

    // trapezoid base cut (row-life frontier proof): top ghost band b ->
    // 4b+3; interior (bands 6,7) -> 24; bottom ghost -> 55-4b.
    const int cutbase = (band < 6) ? ((band << 2) + 3)
                      : ((band < 8) ? GN : (55 - (band << 2)));

    if (tid < NT_) wav[tid] = x[b * NT_ + tid];
    if (tid < NREC_) {
        int rz = rec_loc[(b * NREC_ + tid) * 2 + 0];
        recown[tid] = (rz >= p * IROWS && rz < p * IROWS + IROWS) ? 1 : 0;
    }

    // cf = vp^2*DT^2/DH^2 masked; cf2 = 2 - 4*cf
    v4f cf[4], cf2[4];
#pragma unroll
    for (int i = 0; i < 4; ++i) {
        int gr = grt + i;
        int crow = gr < 0 ? 0 : (gr > 255 ? 255 : gr);
        bool rowok = (gr >= 1) && (gr <= 254);
        v4f vv = *(const v4f*)&vp[crow * NX_ + c0];
        float cc[4];
#pragma unroll
        for (int k = 0; k < 4; ++k) {
            int col = c0 + k;
            float vk = (k == 0) ? vv.x : (k == 1) ? vv.y : (k == 2) ? vv.z : vv.w;
            cc[k] = (rowok && col >= 1 && col <= 254) ? vk * vk * KLAP : 0.f;
        }
        cf[i].x = cc[0]; cf[i].y = cc[1]; cf[i].z = cc[2]; cf[i].w = cc[3];
        cf2[i].x = 2.f - 4.f * cc[0]; cf2[i].y = 2.f - 4.f * cc[1];
        cf2[i].z = 2.f - 4.f * cc[2]; cf2[i].w = 2.f - 4.f * cc[3];
    }

    // source ownership (ghost rows included: ghost evolution must replay it)
    const int sz = src_loc[b * 2 + 0], sx = src_loc[b * 2 + 1];
    const int si = sz - grt;
    const int sj = sx - c0;
    const bool has_src = ((unsigned)si < 4u) && ((unsigned)sj < 4u);
    const bool wave_has_src = __any(has_src);

    // receiver slots: interior owner only (unique writer). pk=(r<<4)|(i<<2)|j
    int rs[RCAP]; int rcnt = 0;
#pragma unroll 1
    for (int r = 0; r < NREC_; ++r) {
        int rz = rec_loc[(b * NREC_ + r) * 2 + 0];
        int rx = rec_loc[(b * NREC_ + r) * 2 + 1];
        int i = rz - grt, j = rx - c0;
        if (rz >= p * IROWS && rz < p * IROWS + IROWS &&
            (unsigned)i < 4u && (unsigned)j < 4u) {
            if (rcnt < RCAP) rs[rcnt] = (r << 4) | (i << 2) | j;
            ++rcnt;
        }
    }
    if (rcnt > RCAP) rcnt = RCAP;
    const bool wave_has_rec = __any(rcnt > 0);
    float* outb = out + (size_t)b * NT_ * NREC_;

    v4f A[4], Bv[4];
    {
        v4f z = {0.f, 0.f, 0.f, 0.f};
#pragma unroll
        for (int i = 0; i < 4; ++i) { A[i] = z; Bv[i] = z; }
    }

    // gbuf slab: [par][blk][lvl][row(0..7)][col]; interior = the slab.
    auto gptr = [&](int e, int bk, int lvl, int rr) -> float* {
        return gbuf + ((((size_t)(e & 1) * NBLK + bk) * 2 + lvl) * 8 + rr) * 256;
    };

    // one step (R13 body verbatim): P <- update(C, P). par = t&1.
    // k = in-round step (1..Gr), cutr = min(cutbase, Gr). Wave-uniform.
    auto step = [&](v4f (&C)[4], v4f (&P)[4], int t, int par, int k, int cutr) {
        if (k <= cutr + 1) {                // publish window = compute window +1
            *(v4f*)&pub[par][0][band][c0] = C[0];  // top row (S halo of band-1)
            *(v4f*)&pub[par][1][band][c0] = C[3];  // bottom row (N halo of band+1)
        }
        __syncthreads();
        if (k > cutr) return;               // band dead for rest of round
        v4f nn, ss;
        if (band > 0)      nn = *(const v4f*)&pub[par][1][band - 1][c0];
        else               { nn.x = 0.f; nn.y = 0.f; nn.z = 0.f; nn.w = 0.f; }
        if (band < NB - 1) ss = *(const v4f*)&pub[par][0][band + 1][c0];
        else               { ss.x = 0.f; ss.y = 0.f; ss.z = 0.f; ss.w = 0.f; }
#pragma unroll
        for (int i = 0; i < 4; ++i) {
            v4f n = (i == 0) ? nn : C[i - 1];
            v4f s = (i == 3) ? ss : C[i + 1];
            float wv = dpp_shr1(C[i].w);   // col c0-1 (lane0 -> 0: cf=0 masks)
            float ev = dpp_shl1(C[i].x);   // col c0+4 (lane63 -> 0: cf=0 masks)
            v4f hn;
            { float sm = (n.x + s.x) + (wv     + C[i].y);
              hn.x = fmaf(cf[i].x, sm, fmaf(cf2[i].x, C[i].x, -P[i].x)); }
            { float sm = (n.y + s.y) + (C[i].x + C[i].z);
              hn.y = fmaf(cf[i].y, sm, fmaf(cf2[i].y, C[i].y, -P[i].y)); }
            { float sm = (n.z + s.z) + (C[i].y + C[i].w);
              hn.z = fmaf(cf[i].z, sm, fmaf(cf2[i].z, C[i].z, -P[i].z)); }
            { float sm = (n.w + s.w) + (C[i].z + ev);
              hn.w = fmaf(cf[i].w, sm, fmaf(cf2[i].w, C[i].w, -P[i].w)); }
            P[i] = hn;
        }
        if (wave_has_src) {
            const float sv = DT2 * wav[t];
#pragma unroll
            for (int i = 0; i < 4; ++i) {
                if (has_src && si == i) {
                    if      (sj == 0) P[i].x += sv;
                    else if (sj == 1) P[i].y += sv;
                    else if (sj == 2) P[i].z += sv;
                    else              P[i].w += sv;
                }
            }
        }
        if (wave_has_rec) {
#pragma unroll
            for (int kk = 0; kk < RCAP; ++kk) {
                if (rcnt > kk) {
                    int pk = rs[kk];
                    int i = (pk >> 2) & 3, j = pk & 3, r = pk >> 4;
                    v4f t01 = (i & 1) ? P[1] : P[0];
                    v4f t23 = (i & 1) ? P[3] : P[2];
                    v4f rw  = (i & 2) ? t23 : t01;
                    float c01 = (j & 1) ? rw.y : rw.x;
                    float c23 = (j & 1) ? rw.w : rw.z;
                    recbuf[k - 1][r] = (j & 2) ? c23 : c01;
                }
            }
        }
        // no trailing barrier: next step uses pub[par^1] (parity double-buffer)
    };

    // early publish of prev level (Bv final before the round's last step):
    // store drain overlaps the final step. Interior bands 6,7.
    auto publish_prev = [&](int e) {
        if (band == 6 || band == 7) {
            int rr0 = (band - 6) << 2;
#pragma unroll
            for (int i = 0; i < 4; ++i)
                store_v4_sys(&gptr(e, blk, 1, rr0 + i)[c0], Bv[i]);
        }
    };

    // three-hop fence-free exchange (R15 pattern, one hop deeper).
    auto exchange = [&](int e) {
        if (band == 6 || band == 7) {      // publish interior, cur level
            int rr0 = (band - 6) << 2;
#pragma unroll
            for (int i = 0; i < 4; ++i)
                store_v4_sys(&gptr(e, blk, 0, rr0 + i)[c0], A[i]);
        }
        __syncthreads();                   // drains each wave's vmcnt first
        if (tid == 0)                      // fire-and-forget; neighbors poll
            __hip_atomic_store(&flags[blk], e + 1, __ATOMIC_RELAXED,
                               __HIP_MEMORY_SCOPE_SYSTEM);
        // ghost refill: band pair -> source block; slab rows (band&1)*4..+3
        {
            int hop = 0;                   // 0 = no refill
            if      (band < 2)  hop = -3;
            else if (band < 4)  hop = -2;
            else if (band < 6)  hop = -1;
            else if (band >= 12) hop = 3;
            else if (band >= 10) hop = 2;
            else if (band >= 8)  hop = 1;
            const int srcp = p + hop;
            if (hop != 0 && srcp >= 0 && srcp < PIECES) {
                const int srcblk = blk + hop;
                if (lane == 0)
                    while (__hip_atomic_load(&flags[srcblk], __ATOMIC_RELAXED,
                                             __HIP_MEMORY_SCOPE_SYSTEM) < e + 1)
                        __builtin_amdgcn_s_sleep(1);
                int rr0 = (band & 1) << 2;
#pragma unroll
                for (int i = 0; i < 4; ++i) {
                    A[i]  = load_v4_sys(&gptr(e, srcblk, 0, rr0 + i)[c0]);
                    Bv[i] = load_v4_sys(&gptr(e, srcblk, 1, rr0 + i)[c0]);
                }
            }
        }
        asm volatile("s_waitcnt vmcnt(0)" ::: "memory");  // rule #18
        __builtin_amdgcn_sched_barrier(0);
        __syncthreads();                   // all waves aligned for next round
    };

    int t = 0;
#pragma unroll 1
    for (int e = 0; e < NRND; ++e) {
        const int Gr   = (e < NRND - 1) ? GN : GL;
        const int cutr = cutbase < Gr ? cutbase : Gr;
#pragma unroll 1
        for (int k = 1; k <= Gr; k += 2) {
            step(A, Bv, t, 0, k, cutr);         // t even: cur=A, par=0
            if (k == Gr - 1 && e < NRND - 1)
                publish_prev(e);                // Bv final; overlap drain
            step(Bv, A, t + 1, 1, k + 1, cutr); // t odd: cur=B, par=1
            t += 2;
        }
        // flush this round's receiver samples (Gr*64 slots, 896 threads)
        __syncthreads();           // recbuf writes came from scattered owners
#pragma unroll 1
        for (int idx = tid; idx < Gr * NREC_; idx += NTHR) {
            int s = idx >> 6, r = idx & 63;
            if (recown[r]) outb[(t - Gr + s) * NREC_ + r] = recbuf[s][r];
        }
        if (e < NRND - 1) exchange(e);
    }
}

extern "C" void kernel_launch(void* const* d_in, const int* in_sizes, int n_in,
                              void* d_out, int out_size, void* d_ws, size_t ws_size,
                              hipStream_t stream) {
    const float* x   = (const float*)d_in[0];
    const float* vp  = (const float*)d_in[1];
    const int*   src = (const int*)d_in[2];
    const int*   rec = (const int*)d_in[3];
    float*       o   = (float*)d_out;
    int*   flags = (int*)d_ws;
    float* gbuf  = (float*)((char*)d_ws + FLAGS_BYTES);
    (void)hipMemsetAsync(d_ws, 0, FLAGS_BYTES, stream);   // flags must start at 0
    hipLaunchKernelGGL(wave_reg_kernel, dim3(NBLK), dim3(NTHR), 0, stream,
                       x, vp, src, rec, o, flags, gbuf);
}

// Round 19
// 283.397 us; speedup vs baseline: 1.1669x; 1.0170x over previous
//
#include <hip/hip_runtime.h>

typedef float v4f __attribute__((ext_vector_type(4)));

namespace {
constexpr int B_     = 8;
constexpr int NT_    = 256;
constexpr int NX_    = 256;
constexpr int NREC_  = 64;
constexpr int PIECES = 16;             // 128 blocks -> 128 CUs active
constexpr int IROWS  = 16;             // interior rows per strip
constexpr int G      = 16;             // ghost width = steps per round
constexpr int ROUNDS = NT_ / G;        // 16 (15 exchanges)
constexpr int NB     = (IROWS + 2 * G) / 4;  // bands per block = 12
constexpr int NTHR   = NB * 64;        // 768 threads
constexpr int NBLK   = B_ * PIECES;    // 128 blocks
constexpr float DT2  = 1e-6f;          // DT*DT
constexpr float KLAP = 1e-8f;          // DT*DT/(DH*DH)
constexpr size_t FLAGS_BYTES = 4096;
constexpr int RCAP = 6;
} // namespace

// lane i <- lane i-1 (shfl_up 1). Lane 0 gets 0.0f (bound_ctrl) -- masked by cf=0.
__device__ __forceinline__ float dpp_shr1(float v) {
    return __int_as_float(__builtin_amdgcn_update_dpp(
        0, __float_as_int(v), 0x138 /*WAVE_SHR1*/, 0xF, 0xF, true));
}
// lane i <- lane i+1 (shfl_down 1). Lane 63 gets 0.0f -- masked by cf=0.
__device__ __forceinline__ float dpp_shl1(float v) {
    return __int_as_float(__builtin_amdgcn_update_dpp(
        0, __float_as_int(v), 0x130 /*WAVE_SHL1*/, 0xF, 0xF, true));
}

// ==== FINAL (R13 champion; R25/R26 resubmits -- R25 failed on container
// acquisition, not on the kernel; this source passed at Round 6:
// 236.5us rocprof / 288.5us bench, absmax 1.862645e-09) ====
// Session model (11 structural experiments, R8-R24):
//   wall = 256 x chain + Nexch x E
//   chain ~= 560ns/step: publish -> barrier -> halo ds_read -> dependent VALU.
//     Floor requires 4-row bands at >=3 waves/SIMD (R16/R20 refute 8-row);
//     sync style irrelevant (R14 skew, R18 async, R19 barrier-free all >=
//     barrier-stepping); 2-step fusion hurts (R17).
//   E ~= 6.4us/exchange: physical MALL round-trip (sc0 sc1 store drain + flag
//     propagation + poll + refill). Invariant under handshake shape (R11),
//     barrier removal (R19), async (R18). G-tuning trades chain vs E 1:1
//     (R13 141+96 = R21 175+64 ~= 237-240us).
//   Latency-hiding via 2 blocks/CU (R22-R24): infeasible in this harness
//     (512-block flag-sync deadlocks under plain launch; cooperative launch
//     does not execute).
// Key wins kept: sc0 sc1 fence-free exchange (R10, -50us: kills the
// buffer_wbl2/inv storms of agent-scope fences on non-coherent per-XCD L2s);
// cf2 algebra 5 VALU/col (R11); wave-uniform src/rec skip (R12); trapezoid
// band deactivation, bit-identical by frontier proof (R13).
__device__ __forceinline__ void store_v4_sys(float* p, v4f v) {
    asm volatile("global_store_dwordx4 %0, %1, off sc0 sc1"
                 :: "v"(p), "v"(v) : "memory");
}
__device__ __forceinline__ v4f load_v4_sys(const float* p) {
    v4f r;
    asm volatile("global_load_dwordx4 %0, %1, off sc0 sc1"
                 : "=v"(r) : "v"(p) : "memory");
    return r;
}

extern "C" __global__
__attribute__((amdgpu_flat_work_group_size(NTHR, NTHR), amdgpu_waves_per_eu(4, 4)))
void wave_reg_kernel(const float* __restrict__ x,
                     const float* __restrict__ vp,
                     const int* __restrict__ src_loc,
                     const int* __restrict__ rec_loc,
                     float* __restrict__ out,
                     int* __restrict__ flags,   // [128] monotone round counters
                     float* __restrict__ gbuf)  // [par2][128][lvl2][16][256]
{
    __shared__ float pub[2][2][NB][256];   // 48 KB: [par][top/bot row][band][col]
    __shared__ float wav[NT_];             // 1 KB wavelet
    __shared__ float recbuf[G][NREC_];     // 4 KB receiver staging (per round)
    __shared__ unsigned char recown[NREC_];// per-rec ownership of this block

    const int bid  = blockIdx.x;
    const int b    = bid & 7;
    const int p    = bid >> 3;             // 0..15
    const int blk  = b * PIECES + p;
    const int tid  = threadIdx.x;
    const int band = tid >> 6;             // wave id 0..11 -> 4 ext rows
    const int lane = tid & 63;
    const int c0   = lane << 2;            // first owned col (0..252)
    const int grt  = p * IROWS - G + (band << 2);  // global row of owned row 0

    // trapezoid cutoff: band computes at in-round step k (1-based) iff k<=cut;
    // publishes iff k<=cut+1. Wave-uniform.
    const int cut = (band < 4) ? ((band << 2) + 3)
                  : ((band < 8) ? G : (47 - (band << 2)));

    if (tid < NT_) wav[tid] = x[b * NT_ + tid];
    if (tid < NREC_) {
        int rz = rec_loc[(b * NREC_ + tid) * 2 + 0];
        recown[tid] = (rz >= p * IROWS && rz < p * IROWS + IROWS) ? 1 : 0;
    }

    // cf = vp^2*DT^2/DH^2, zeroed at Dirichlet boundary + out-of-domain rows.
    // cf2 = 2 - 4*cf: hn = cf*((N+S)+(E+W)) + (cf2*C - P)  [5 VALU/col]
    v4f cf[4], cf2[4];
#pragma unroll
    for (int i = 0; i < 4; ++i) {
        int gr = grt + i;
        int crow = gr < 0 ? 0 : (gr > 255 ? 255 : gr);
        bool rowok = (gr >= 1) && (gr <= 254);
        v4f vv = *(const v4f*)&vp[crow * NX_ + c0];
        float cc[4];
#pragma unroll
        for (int k = 0; k < 4; ++k) {
            int col = c0 + k;
            float vk = (k == 0) ? vv.x : (k == 1) ? vv.y : (k == 2) ? vv.z : vv.w;
            cc[k] = (rowok && col >= 1 && col <= 254) ? vk * vk * KLAP : 0.f;
        }
        cf[i].x = cc[0]; cf[i].y = cc[1]; cf[i].z = cc[2]; cf[i].w = cc[3];
        cf2[i].x = 2.f - 4.f * cc[0]; cf2[i].y = 2.f - 4.f * cc[1];
        cf2[i].z = 2.f - 4.f * cc[2]; cf2[i].w = 2.f - 4.f * cc[3];
    }

    // source ownership (ghost rows included: ghost evolution must replay it)
    const int sz = src_loc[b * 2 + 0], sx = src_loc[b * 2 + 1];
    const int si = sz - grt;               // 0..3 if owned row
    const int sj = sx - c0;                // 0..3 if owned col
    const bool has_src = ((unsigned)si < 4u) && ((unsigned)sj < 4u);
    const bool wave_has_src = __any(has_src);   // wave-uniform -> branch skips

    // receiver slots: interior owner only (unique writer). pk=(r<<4)|(i<<2)|j
    int rs[RCAP]; int rcnt = 0;
#pragma unroll 1
    for (int r = 0; r < NREC_; ++r) {
        int rz = rec_loc[(b * NREC_ + r) * 2 + 0];
        int rx = rec_loc[(b * NREC_ + r) * 2 + 1];
        int i = rz - grt, j = rx - c0;
        if (rz >= p * IROWS && rz < p * IROWS + IROWS &&
            (unsigned)i < 4u && (unsigned)j < 4u) {
            if (rcnt < RCAP) rs[rcnt] = (r << 4) | (i << 2) | j;
            ++rcnt;
        }
    }
    if (rcnt > RCAP) rcnt = RCAP;
    const bool wave_has_rec = __any(rcnt > 0);  // wave-uniform -> branch skips
    float* outb = out + (size_t)b * NT_ * NREC_;

    v4f A[4], Bv[4];
    {
        v4f z = {0.f, 0.f, 0.f, 0.f};
#pragma unroll
        for (int i = 0; i < 4; ++i) { A[i] = z; Bv[i] = z; }
    }

    // gbuf slab pointer: [par][blk][lvl][row][col]; interior = the slab.
    auto gptr = [&](int e, int bk, int lvl, int rr) -> float* {
        return gbuf + ((((size_t)(e & 1) * NBLK + bk) * 2 + lvl) * 16 + rr) * 256;
    };

    // one step: P <- update(C, P); P becomes current. par = t&1.
    // k = in-round step (1..G), wave-uniform.
    auto step = [&](v4f (&C)[4], v4f (&P)[4], int t, int par) {
        const int k = (t & (G - 1)) + 1;
        if (k <= cut + 1) {                 // publish window = compute window +1
            *(v4f*)&pub[par][0][band][c0] = C[0];  // top row (south halo of band-1)
            *(v4f*)&pub[par][1][band][c0] = C[3];  // bottom row (north halo of band+1)
        }
        __syncthreads();
        if (k > cut) return;                // all this band's rows are dead now
        v4f nn, ss;
        if (band > 0)      nn = *(const v4f*)&pub[par][1][band - 1][c0];
        else               { nn.x = 0.f; nn.y = 0.f; nn.z = 0.f; nn.w = 0.f; }
        if (band < NB - 1) ss = *(const v4f*)&pub[par][0][band + 1][c0];
        else               { ss.x = 0.f; ss.y = 0.f; ss.z = 0.f; ss.w = 0.f; }
#pragma unroll
        for (int i = 0; i < 4; ++i) {
            v4f n = (i == 0) ? nn : C[i - 1];
            v4f s = (i == 3) ? ss : C[i + 1];
            float wv = dpp_shr1(C[i].w);   // col c0-1 (lane0 -> 0: cf=0 masks)
            float ev = dpp_shl1(C[i].x);   // col c0+4 (lane63 -> 0: cf=0 masks)
            v4f hn;
            { float sm = (n.x + s.x) + (wv     + C[i].y);
              hn.x = fmaf(cf[i].x, sm, fmaf(cf2[i].x, C[i].x, -P[i].x)); }
            { float sm = (n.y + s.y) + (C[i].x + C[i].z);
              hn.y = fmaf(cf[i].y, sm, fmaf(cf2[i].y, C[i].y, -P[i].y)); }
            { float sm = (n.z + s.z) + (C[i].y + C[i].w);
              hn.z = fmaf(cf[i].z, sm, fmaf(cf2[i].z, C[i].z, -P[i].z)); }
            { float sm = (n.w + s.w) + (C[i].z + ev);
              hn.w = fmaf(cf[i].w, sm, fmaf(cf2[i].w, C[i].w, -P[i].w)); }
            P[i] = hn;
        }
        // source injection: only the wave containing the source pays for it
        if (wave_has_src) {
            const float sv = DT2 * wav[t];
#pragma unroll
            for (int i = 0; i < 4; ++i) {
                if (has_src && si == i) {
                    if      (sj == 0) P[i].x += sv;
                    else if (sj == 1) P[i].y += sv;
                    else if (sj == 2) P[i].z += sv;
                    else              P[i].w += sv;
                }
            }
        }
        // receiver gather (NEW level, registers) -> LDS staging.
        if (wave_has_rec) {
#pragma unroll
            for (int kk = 0; kk < RCAP; ++kk) {
                if (rcnt > kk) {
                    int pk = rs[kk];
                    int i = (pk >> 2) & 3, j = pk & 3, r = pk >> 4;
                    v4f t01 = (i & 1) ? P[1] : P[0];
                    v4f t23 = (i & 1) ? P[3] : P[2];
                    v4f rw  = (i & 2) ? t23 : t01;
                    float c01 = (j & 1) ? rw.y : rw.x;
                    float c23 = (j & 1) ? rw.w : rw.z;
                    recbuf[t & (G - 1)][r] = (j & 2) ? c23 : c01;
                }
            }
        }
        // no trailing barrier: next step uses pub[par^1] (parity double-buffer)
    };

    // early publish of prev level (Bv is final before the round's last step):
    // its store drain overlaps the final step's compute. Interior bands only.
    auto publish_prev = [&](int e) {
        if (band >= 4 && band < 8) {
            int rr0 = (band - 4) << 2;
#pragma unroll
            for (int i = 0; i < 4; ++i)
                store_v4_sys(&gptr(e, blk, 1, rr0 + i)[c0], Bv[i]);
        }
    };

    // exchange after round e: publish cur level, drain via barrier's vmcnt(0),
    // flag (fire-and-forget), ghost waves poll their neighbor + refill.
    auto exchange = [&](int e) {
        if (band >= 4 && band < 8) {       // publish interior, cur level
            int rr0 = (band - 4) << 2;
#pragma unroll
            for (int i = 0; i < 4; ++i)
                store_v4_sys(&gptr(e, blk, 0, rr0 + i)[c0], A[i]);
        }
        // barrier semantics: each wave drains vmcnt(0) (all sc0 sc1 stores,
        // incl. early Bv publish, ack'd at coherence point) before s_barrier.
        __syncthreads();
        if (tid == 0)                      // fire-and-forget; neighbors poll
            __hip_atomic_store(&flags[blk], e + 1, __ATOMIC_RELAXED,
                               __HIP_MEMORY_SCOPE_SYSTEM);
        if (band < 4 && p > 0) {           // top ghost <- north (blk-1) interior
            if (lane == 0)
                while (__hip_atomic_load(&flags[blk - 1], __ATOMIC_RELAXED,
                                         __HIP_MEMORY_SCOPE_SYSTEM) < e + 1)
                    __builtin_amdgcn_s_sleep(1);
            int rr0 = band << 2;           // ext rows 0..15 == slab rows 0..15
#pragma unroll
            for (int i = 0; i < 4; ++i) {
                A[i]  = load_v4_sys(&gptr(e, blk - 1, 0, rr0 + i)[c0]);
                Bv[i] = load_v4_sys(&gptr(e, blk - 1, 1, rr0 + i)[c0]);
            }
        }
        if (band >= 8 && p < PIECES - 1) { // bottom ghost <- south (blk+1)
            if (lane == 0)
                while (__hip_atomic_load(&flags[blk + 1], __ATOMIC_RELAXED,
                                         __HIP_MEMORY_SCOPE_SYSTEM) < e + 1)
                    __builtin_amdgcn_s_sleep(1);
            int rr0 = (band - 8) << 2;     // ext rows 32..47 == slab rows 0..15
#pragma unroll
            for (int i = 0; i < 4; ++i) {
                A[i]  = load_v4_sys(&gptr(e, blk + 1, 0, rr0 + i)[c0]);
                Bv[i] = load_v4_sys(&gptr(e, blk + 1, 1, rr0 + i)[c0]);
            }
        }
        // asm loads are opaque to compiler waitcnt logic: drain before any use
        // of A/Bv and pin the order (rule #18).
        asm volatile("s_waitcnt vmcnt(0)" ::: "memory");
        __builtin_amdgcn_sched_barrier(0);
        __syncthreads();                   // all waves aligned for next round
    };

    int t = 0;
#pragma unroll 1
    for (int e = 0; e < ROUNDS; ++e) {
#pragma unroll 1
        for (int s = 0; s < G; s += 2) {
            step(A, Bv, t, 0);      // t even: cur=A, par=0
            if (s == G - 2 && e < ROUNDS - 1)
                publish_prev(e);    // Bv = lvl t_end-1 is final; overlap drain
            step(Bv, A, t + 1, 1);  // t odd:  cur=B, par=1
            t += 2;
        }
        // flush this round's receiver samples (G*NREC=1024 slots, 768 threads)
        __syncthreads();           // recbuf writes came from scattered owners
#pragma unroll 1
        for (int idx = tid; idx < G * NREC_; idx += NTHR) {
            int s = idx >> 6, r = idx & 63;
            if (recown[r]) outb[(e * G + s) * NREC_ + r] = recbuf[s][r];
        }
        // next recbuf writes are ordered behind exchange's barriers;
        // last round ends the kernel.
        if (e < ROUNDS - 1) exchange(e);
    }
}

extern "C" void kernel_launch(void* const* d_in, const int* in_sizes, int n_in,
                              void* d_out, int out_size, void* d_ws, size_t ws_size,
                              hipStream_t stream) {
    const float* x   = (const float*)d_in[0];
    const float* vp  = (const float*)d_in[1];
    const int*   src = (const int*)d_in[2];
    const int*   rec = (const int*)d_in[3];
    float*       o   = (float*)d_out;
    int*   flags = (int*)d_ws;
    float* gbuf  = (float*)((char*)d_ws + FLAGS_BYTES);
    (void)hipMemsetAsync(d_ws, 0, FLAGS_BYTES, stream);   // flags must start at 0
    hipLaunchKernelGGL(wave_reg_kernel, dim3(NBLK), dim3(NTHR), 0, stream,
                       x, vp, src, rec, o, flags, gbuf);
}